// Round 1
// baseline (195.332 us; speedup 1.0000x reference)
//
#include <hip/hip_runtime.h>

#define HQ 32
#define HKV 8
#define DH 128
#define WIN 256
#define META 128

typedef __attribute__((ext_vector_type(8))) __bf16 bf16x8;
typedef __attribute__((ext_vector_type(16))) float f32x16;

__device__ __forceinline__ unsigned short f2bf(float f) {
  unsigned u = __float_as_uint(f);
  u += 0x7FFFu + ((u >> 16) & 1u);
  return (unsigned short)(u >> 16);
}

// One block = one head x 128 q-rows. 4 waves, each owns 32 q-rows.
// Flash-style: iterate 32-row KV tiles (4 meta tiles + sliding-window tiles).
__global__ __launch_bounds__(256, 2)
void attn_fused(const float* __restrict__ Qg, const float* __restrict__ Kg,
                const float* __restrict__ Vg, float* __restrict__ Og, int S) {
  const int h    = blockIdx.x;          // 0..31
  const int q0   = blockIdx.y * 128;    // q-block start
  const int hk   = h >> 2;              // GQA: repeat(k, 4, axis=1) -> kv head = h/4
  const int tid  = threadIdx.x;
  const int lane = tid & 63;
  const int wave = tid >> 6;
  const int ln31 = lane & 31;
  const int hi   = lane >> 5;

  __shared__ unsigned short Qs[128][136];     // q bf16, rope'd; +8 pad (16B-aligned rows)
  __shared__ unsigned short Ks[32][136];      // k tile bf16, rope'd
  __shared__ unsigned short Vs[128][40];      // v tile TRANSPOSED: Vs[d][kv]
  __shared__ unsigned short Ps[4][32][40];    // per-wave P (bf16) for C->A layout xform
  __shared__ float invf[64];

  if (tid < 64) invf[tid] = __expf(-0.14391156831212787f * (float)tid); // 10000^(-t/64)
  __syncthreads();

  // ---- stage Q (rope -> bf16 -> LDS), 2 threads per row ----
  {
    const int r  = tid >> 1;
    const int c0 = (tid & 1) * 32;
    const int gq = q0 + r;
    const float pos = (float)gq;
    const float* qrow = Qg + (size_t)gq * (HQ * DH) + (size_t)h * DH;
    #pragma unroll
    for (int c = c0; c < c0 + 32; c += 8) {
      float xs[8], ys[8];
      *(float4*)&xs[0] = *(const float4*)(qrow + c);
      *(float4*)&xs[4] = *(const float4*)(qrow + c + 4);
      *(float4*)&ys[0] = *(const float4*)(qrow + c + 64);
      *(float4*)&ys[4] = *(const float4*)(qrow + c + 68);
      unsigned short lo[8], hb[8];
      #pragma unroll
      for (int j = 0; j < 8; ++j) {
        float sv, cv;
        __sincosf(pos * invf[c + j], &sv, &cv);
        lo[j] = f2bf(xs[j] * cv - ys[j] * sv);   // out[c]    = x*cos - y*sin
        hb[j] = f2bf(ys[j] * cv + xs[j] * sv);   // out[c+64] = y*cos + x*sin
      }
      __builtin_memcpy(&Qs[r][c], lo, 16);
      __builtin_memcpy(&Qs[r][c + 64], hb, 16);
    }
  }

  // KV tile schedule: 4 meta tiles (kv 0..127) + window tiles [max(128,q0-256), q0+128)
  int wstart = q0 - WIN; if (wstart < META) wstart = META;
  int nwin = (q0 + 128 - wstart) / 32; if (nwin < 0) nwin = 0;
  const int ntiles = 4 + nwin;

  const int qw0 = q0 + wave * 32;   // this wave's q rows
  f32x16 acc[4];
  #pragma unroll
  for (int d = 0; d < 4; ++d) {
    #pragma unroll
    for (int r = 0; r < 16; ++r) acc[d][r] = 0.f;
  }
  float m_i[16], l_i[16];
  #pragma unroll
  for (int r = 0; r < 16; ++r) { m_i[r] = -1e30f; l_i[r] = 0.f; }

  for (int t = 0; t < ntiles; ++t) {
    const int kv0 = (t < 4) ? t * 32 : wstart + (t - 4) * 32;

    __syncthreads();  // previous tile's PV readers done before restaging K/V

    // ---- stage K tile (rope), 8 threads per row ----
    {
      const int r  = tid >> 3;
      const int c0 = (tid & 7) * 8;
      const int gk = kv0 + r;
      const float pos = (float)gk;
      const float* krow = Kg + (size_t)gk * (HKV * DH) + (size_t)hk * DH;
      float xs[8], ys[8];
      *(float4*)&xs[0] = *(const float4*)(krow + c0);
      *(float4*)&xs[4] = *(const float4*)(krow + c0 + 4);
      *(float4*)&ys[0] = *(const float4*)(krow + c0 + 64);
      *(float4*)&ys[4] = *(const float4*)(krow + c0 + 68);
      unsigned short lo[8], hb[8];
      #pragma unroll
      for (int j = 0; j < 8; ++j) {
        float sv, cv;
        __sincosf(pos * invf[c0 + j], &sv, &cv);
        lo[j] = f2bf(xs[j] * cv - ys[j] * sv);
        hb[j] = f2bf(ys[j] * cv + xs[j] * sv);
      }
      __builtin_memcpy(&Ks[r][c0], lo, 16);
      __builtin_memcpy(&Ks[r][c0 + 64], hb, 16);
    }
    // ---- stage V tile transposed: Vs[d][kv], packed b32 writes (2 rows/thread) ----
    {
      const int rp = (tid & 15) * 2;
      const int c0 = (tid >> 4) * 8;
      const float* v0 = Vg + (size_t)(kv0 + rp) * (HKV * DH) + (size_t)hk * DH + c0;
      const float* v1 = v0 + HKV * DH;
      float a0[8], a1[8];
      *(float4*)&a0[0] = *(const float4*)(v0);
      *(float4*)&a0[4] = *(const float4*)(v0 + 4);
      *(float4*)&a1[0] = *(const float4*)(v1);
      *(float4*)&a1[4] = *(const float4*)(v1 + 4);
      #pragma unroll
      for (int j = 0; j < 8; ++j) {
        unsigned pk = ((unsigned)f2bf(a1[j]) << 16) | (unsigned)f2bf(a0[j]);
        *(unsigned*)&Vs[c0 + j][rp] = pk;
      }
    }
    __syncthreads();

    const bool active = (kv0 <= qw0 + 31);  // tile not fully above the causal diag
    if (active) {
      // ---- S = Q K^T (32x32), 8 MFMAs over D=128 ----
      f32x16 s;
      #pragma unroll
      for (int r = 0; r < 16; ++r) s[r] = 0.f;
      const unsigned short* qb = &Qs[wave * 32 + ln31][0];  // A: m = lane&31
      const unsigned short* kb = &Ks[ln31][0];              // B: n = lane&31
      const int kh = hi * 8;                                // k = (lane>>5)*8 + j
      #pragma unroll
      for (int kk = 0; kk < 8; ++kk) {
        bf16x8 a = *(const bf16x8*)(qb + kk * 16 + kh);
        bf16x8 b = *(const bf16x8*)(kb + kk * 16 + kh);
        s = __builtin_amdgcn_mfma_f32_32x32x16_bf16(a, b, s, 0, 0, 0);
      }
      // ---- mask + online softmax (rows live in 32-lane halves) ----
      const int col = kv0 + ln31;
      float alpha[16];
      #pragma unroll
      for (int r = 0; r < 16; ++r) {
        const int row  = (r & 3) + 8 * (r >> 2) + hi * 4;   // C layout row
        const int qrow = qw0 + row;
        float sv = s[r] * 0.08838834764831845f;
        const bool valid = (col <= qrow) && (((qrow - col) <= WIN) || (col < META));
        sv = valid ? sv : -1e30f;
        float mx = sv;
        mx = fmaxf(mx, __shfl_xor(mx, 1));
        mx = fmaxf(mx, __shfl_xor(mx, 2));
        mx = fmaxf(mx, __shfl_xor(mx, 4));
        mx = fmaxf(mx, __shfl_xor(mx, 8));
        mx = fmaxf(mx, __shfl_xor(mx, 16));
        const float mnew = fmaxf(m_i[r], mx);
        const float a_ = __expf(m_i[r] - mnew);   // exp(-huge)=0 on first real tile
        float p = valid ? __expf(sv - mnew) : 0.f; // avoid exp(0)=1 on all-masked rows
        float ps = p;
        ps += __shfl_xor(ps, 1);
        ps += __shfl_xor(ps, 2);
        ps += __shfl_xor(ps, 4);
        ps += __shfl_xor(ps, 8);
        ps += __shfl_xor(ps, 16);
        l_i[r] = l_i[r] * a_ + ps;
        m_i[r] = mnew;
        alpha[r] = a_;
        Ps[wave][row][ln31] = f2bf(p);            // C layout -> row-major LDS
      }
      #pragma unroll
      for (int d = 0; d < 4; ++d) {
        #pragma unroll
        for (int r = 0; r < 16; ++r) acc[d][r] *= alpha[r];
      }
    }
    __syncthreads();  // P writes (cross-lane) ordered before A-frag reads

    if (active) {
      // ---- O += P V : A = P (M=q,K=kv), B = Vs[d][kv] (N=d) ----
      const unsigned short* pb = &Ps[wave][ln31][0];
      const int kh = hi * 8;
      bf16x8 pa0 = *(const bf16x8*)(pb + kh);        // kv 0..15
      bf16x8 pa1 = *(const bf16x8*)(pb + 16 + kh);   // kv 16..31
      #pragma unroll
      for (int d = 0; d < 4; ++d) {
        const unsigned short* vb = &Vs[d * 32 + ln31][0];
        bf16x8 b0 = *(const bf16x8*)(vb + kh);
        bf16x8 b1 = *(const bf16x8*)(vb + 16 + kh);
        acc[d] = __builtin_amdgcn_mfma_f32_32x32x16_bf16(pa0, b0, acc[d], 0, 0, 0);
        acc[d] = __builtin_amdgcn_mfma_f32_32x32x16_bf16(pa1, b1, acc[d], 0, 0, 0);
      }
    }
  }

  // ---- epilogue: O /= l, coalesced fp32 stores ----
  #pragma unroll
  for (int r = 0; r < 16; ++r) {
    const int row = (r & 3) + 8 * (r >> 2) + hi * 4;
    const int gq  = qw0 + row;
    const float inv = 1.0f / l_i[r];
    float* orow = Og + (size_t)gq * (HQ * DH) + (size_t)h * DH + ln31;
    #pragma unroll
    for (int d = 0; d < 4; ++d) orow[d * 32] = acc[d][r] * inv;
  }
}

extern "C" void kernel_launch(void* const* d_in, const int* in_sizes, int n_in,
                              void* d_out, int out_size, void* d_ws, size_t ws_size,
                              hipStream_t stream) {
  const float* Qg = (const float*)d_in[0];
  const float* Kg = (const float*)d_in[1];
  const float* Vg = (const float*)d_in[2];
  float* Og = (float*)d_out;
  const int S = in_sizes[0] / (HQ * DH);   // 2176
  dim3 grid(HQ, S / 128);                  // 32 heads x 17 q-blocks
  attn_fused<<<grid, dim3(256), 0, stream>>>(Qg, Kg, Vg, Og, S);
}